// Round 1
// baseline (81809.888 us; speedup 1.0000x reference)
//
#include <hip/hip_runtime.h>
#include <cstdint>
#include <cstddef>

// Problem constants (from reference setup_inputs)
#define BB   64
#define TT   400
#define NN   1024
#define NIN  128
#define NOUT 32
#define DD   3
#define LL   5          // ring length = max(delays)+1 = 5   (delays = [1,2,4])

#define ALPHA_MEM     0.95f
#define ALPHA_MEM_OUT 0.95f
#define ALPHA_P       0.99f

// ---------------------------------------------------------------------------
// Kernel 1: materialize W[d][e][n] = dmap[d][e][n] * (sign[e] * |w[e][n]|)
// ---------------------------------------------------------------------------
__global__ void build_W(const float* __restrict__ w,
                        const float* __restrict__ w_signs,
                        const float* __restrict__ dmap,
                        float* __restrict__ W) {
    int idx = blockIdx.x * blockDim.x + threadIdx.x;
    if (idx >= DD * NN * NN) return;
    int en = idx % (NN * NN);
    int e  = en / NN;
    W[idx] = dmap[idx] * (w_signs[e] * fabsf(w[en]));
}

// ---------------------------------------------------------------------------
// Kernel 2: the full sequential scan. One block per batch, one thread per
// neuron. Ring buffers in LDS. Spike-list-driven sparse recurrent sum.
// ---------------------------------------------------------------------------
__global__ __launch_bounds__(1024) void snn_scan(
    const float* __restrict__ inputs,   // (B,T,NIN)
    const float* __restrict__ w_in,     // (NIN,N)
    const float* __restrict__ w_out,    // (N,NOUT)
    const float* __restrict__ p,        // (N)
    const int*   __restrict__ delays,   // (D)  -- expected {1,2,4}, all in [1,L-1]
    const float* __restrict__ W,        // (D,N,N) materialized
    float* __restrict__ out)            // (B,T,NOUT)
{
    __shared__ float          a_buf[LL * NN];      // out*(1+w_p) ring, 20 KB
    __shared__ unsigned short idx_list[LL * NN];   // spike index lists, 10 KB
    __shared__ int            s_count[LL];
    __shared__ int            wave_cnt[16];
    __shared__ float          s_in[NIN];

    const int tid  = threadIdx.x;      // == neuron index n
    const int b    = blockIdx.x;       // batch
    const int lane = tid & 63;
    const int wid  = tid >> 6;

    float mem = 0.0f;
    float wp  = 0.0f;
    const float pn    = p[tid];
    const float deprn = (pn < 0.0f) ? 1.0f : 0.0f;
    const int d0 = delays[0], d1 = delays[1], d2 = delays[2];
    float r = 0.0f;                    // readout state (wave 0, lanes < NOUT)

    if (tid < LL) s_count[tid] = 0;    // read only after first __syncthreads

    const float* inp_b = inputs + (size_t)b * TT * NIN;
    float*       out_b = out    + (size_t)b * TT * NOUT;

    for (int t = 0; t < TT; ++t) {
        const int slot = t % LL;

        // ---- phase A: spikes, ring write, ballot, input staging, w_p update
        const float x    = mem - 1.0f;
        const bool  spk  = (x > 0.0f);
        const float outv = spk ? 1.0f : 0.0f;
        a_buf[slot * NN + tid] = spk ? (1.0f + wp) : 0.0f;
        const unsigned long long mask = __ballot(spk);
        if (lane == 0) wave_cnt[wid] = __popcll(mask);
        if (tid < NIN) s_in[tid] = inp_b[t * NIN + tid];
        wp = ALPHA_P * wp + outv * pn * (1.0f + deprn * wp);   // uses old wp
        __syncthreads();

        // ---- phase B: list append (current slot), recurrent sum (old slots),
        //      input projection, mem update, delayed readout
        int basew = 0;
        for (int w2 = 0; w2 < wid; ++w2) basew += wave_cnt[w2];
        if (spk) {
            const int prefix = __popcll(mask & ((1ull << lane) - 1ull));
            idx_list[slot * NN + basew + prefix] = (unsigned short)tid;
        }
        if (tid == 0) {
            int tot = 0;
            for (int w2 = 0; w2 < 16; ++w2) tot += wave_cnt[w2];
            s_count[slot] = tot;
        }

        // recurrent input: syn[n] = sum_d sum_{spiking e} a * W[d][e][n]
        // (skipping exact zeros == dense sum bit-for-bit)
        float syn = 0.0f;
        {
            const int ss0 = (t - d0 + LL) % LL;
            const int ss1 = (t - d1 + LL) % LL;
            const int ss2 = (t - d2 + LL) % LL;
            const int slots3[3] = { ss0, ss1, ss2 };
            for (int d = 0; d < DD; ++d) {
                const int s   = slots3[d];
                const int cnt = s_count[s];                 // stable (built pre-sync)
                const float* __restrict__ Wd = W + (size_t)d * NN * NN;
                for (int i = 0; i < cnt; ++i) {
                    const int   e  = idx_list[s * NN + i];  // LDS broadcast
                    const float av = a_buf[s * NN + e];     // LDS broadcast
                    syn = fmaf(av, Wd[e * NN + tid], syn);  // coalesced global
                }
            }
        }

        // input projection: inp_t[n] = sum_c s_in[c] * w_in[c][n]
        float ia = 0.0f;
        #pragma unroll 8
        for (int c = 0; c < NIN; ++c)
            ia = fmaf(s_in[c], w_in[c * NN + tid], ia);

        mem = ALPHA_MEM * mem + ia + syn - outv;

        // readout for step t-1 (its spike list is complete and barrier-stable)
        if (tid < NOUT && t > 0) {
            const int ps  = (t - 1) % LL;
            const int cnt = s_count[ps];
            float h = 0.0f;
            for (int i = 0; i < cnt; ++i)
                h += w_out[(int)idx_list[ps * NN + i] * NOUT + tid];
            r = ALPHA_MEM_OUT * r + h;
            out_b[(t - 1) * NOUT + tid] = r;
        }

        __syncthreads();   // protects ring/list/s_in/wave_cnt reuse next step
    }

    // final readout for t = T-1
    if (tid < NOUT) {
        const int ps  = (TT - 1) % LL;
        const int cnt = s_count[ps];
        float h = 0.0f;
        for (int i = 0; i < cnt; ++i)
            h += w_out[(int)idx_list[ps * NN + i] * NOUT + tid];
        r = ALPHA_MEM_OUT * r + h;
        out_b[(TT - 1) * NOUT + tid] = r;
    }
}

// ---------------------------------------------------------------------------
extern "C" void kernel_launch(void* const* d_in, const int* in_sizes, int n_in,
                              void* d_out, int out_size, void* d_ws, size_t ws_size,
                              hipStream_t stream) {
    const float* inputs  = (const float*)d_in[0];  // (B,T,NIN)
    const float* w       = (const float*)d_in[1];  // (N,N)
    const float* w_in    = (const float*)d_in[2];  // (NIN,N)
    const float* w_out   = (const float*)d_in[3];  // (N,NOUT)
    const float* w_signs = (const float*)d_in[4];  // (N)
    const float* dmap    = (const float*)d_in[5];  // (D,N,N)
    const float* p       = (const float*)d_in[6];  // (N)
    const int*   delays  = (const int*)d_in[7];    // (D)

    float* W = (float*)d_ws;                       // D*N*N floats = 12.6 MB
    float* outp = (float*)d_out;                   // (B,T,NOUT) fp32

    {
        const int total = DD * NN * NN;
        build_W<<<(total + 255) / 256, 256, 0, stream>>>(w, w_signs, dmap, W);
    }
    snn_scan<<<BB, 1024, 0, stream>>>(inputs, w_in, w_out, p, delays, W, outp);
}

// Round 2
// 54624.103 us; speedup vs baseline: 1.4977x; 1.4977x over previous
//
#include <hip/hip_runtime.h>
#include <hip/hip_cooperative_groups.h>
#include <cstdint>
#include <cstddef>

namespace cg = cooperative_groups;

// Problem constants
#define BB   64
#define TT   400
#define NN   1024
#define NIN  128
#define NOUT 32
#define DD   3
#define LL   5          // ring length = max(delays)+1, delays = [1,2,4]
#define NCH  4          // chunks per batch
#define CHW  256        // neurons per chunk
#define NTH  256        // threads per block (== CHW)

#define ALPHA_MEM     0.95f
#define ALPHA_MEM_OUT 0.95f
#define ALPHA_P       0.99f

// ---------------------------------------------------------------------------
// W[d][e][n] = dmap[d][e][n] * (sign[e] * |w[e][n]|)
// ---------------------------------------------------------------------------
__global__ void build_W(const float* __restrict__ w,
                        const float* __restrict__ w_signs,
                        const float* __restrict__ dmap,
                        float* __restrict__ W) {
    int idx = blockIdx.x * blockDim.x + threadIdx.x;
    if (idx >= DD * NN * NN) return;
    int en = idx % (NN * NN);
    int e  = en / NN;
    W[idx] = dmap[idx] * (w_signs[e] * fabsf(w[en]));
}

// inp[b][t][n] = sum_c inputs[b][t][c] * w_in[c][n]  (ascending c, fmaf chain)
__global__ void gemm_in(const float* __restrict__ inputs,
                        const float* __restrict__ w_in,
                        float* __restrict__ inp) {
    int idx = blockIdx.x * blockDim.x + threadIdx.x;   // BB*TT*NN total
    int n  = idx & (NN - 1);
    int bt = idx >> 10;
    const float* row = inputs + (size_t)bt * NIN;      // broadcast within block
    float acc = 0.0f;
    #pragma unroll 8
    for (int c = 0; c < NIN; ++c)
        acc = fmaf(row[c], w_in[c * NN + n], acc);
    inp[idx] = acc;
}

__global__ void zero_f(float* __restrict__ ptr, int n) {
    int i = blockIdx.x * blockDim.x + threadIdx.x;
    if (i < n) ptr[i] = 0.0f;
}

// ---------------------------------------------------------------------------
// Cooperative scan: 256 blocks (4 chunks x 64 batches), 256 threads.
// Thread owns neuron col = chunk*256 + tid of batch b. One grid.sync per step.
// ---------------------------------------------------------------------------
__global__ __launch_bounds__(NTH) void snn_scan(
    const float* __restrict__ inputs,   // (B,T,NIN)
    const float* __restrict__ w_in,     // (NIN,N)
    const float* __restrict__ w_out,    // (N,NOUT)
    const float* __restrict__ p,        // (N)
    const int*   __restrict__ delays,   // (D)
    const float* __restrict__ W,        // (D,N,N) materialized (use_W=1)
    const float* __restrict__ w_raw,    // (N,N)   fallback (use_W=0)
    const float* __restrict__ w_signs,  // (N)     fallback
    const float* __restrict__ dmap,     // (D,N,N) fallback
    float*       __restrict__ g_a,      // (LL,B,N) global spike-value ring
    const float* __restrict__ inp_pre,  // (B,T,N) or null
    float*       __restrict__ out,      // (B,T,NOUT)
    int use_pre, int use_W)
{
    __shared__ float          list_a[LL * NN];   // 20 KB: a = out*(1+wp) per spike
    __shared__ unsigned short list_e[LL * NN];   // 10 KB: spiking neuron indices
    __shared__ int            s_count[LL];
    __shared__ int            wcnt[NTH / 64];
    __shared__ float          s_in[NIN];
    __shared__ float          s_sign[NN];        // 4 KB, used only if use_W==0

    cg::grid_group grid = cg::this_grid();

    const int tid   = threadIdx.x;
    const int chunk = blockIdx.x & (NCH - 1);    // same chunk per XCD (blockIdx%8 heuristic)
    const int b     = blockIdx.x >> 2;
    const int lane  = tid & 63;
    const int wid   = tid >> 6;
    const int col   = chunk * CHW + tid;         // owned neuron

    float mem = 0.0f, wp = 0.0f, r = 0.0f;
    const float pn    = p[col];
    const float deprn = (pn < 0.0f) ? 1.0f : 0.0f;
    const int d0 = delays[0], d1 = delays[1], d2 = delays[2];

    if (tid < LL) s_count[tid] = 0;
    if (!use_W) {
        #pragma unroll
        for (int k = tid; k < NN; k += NTH) s_sign[k] = w_signs[k];
    }
    __syncthreads();

    const float* inp_b = inputs + (size_t)b * TT * NIN;
    float*       out_b = out    + (size_t)b * TT * NOUT;

    for (int t = 0; t < TT; ++t) {
        const int slot = t % LL;

        // ---- phase 1: spike + publish a-value to global ring, update w_p
        const bool  spk  = (mem - 1.0f) > 0.0f;
        const float outv = spk ? 1.0f : 0.0f;
        float a = spk ? (1.0f + wp) : 0.0f;
        if (spk && a == 0.0f) a = -0.0f;         // keep spike detectable by bit pattern
        g_a[(size_t)slot * BB * NN + (size_t)b * NN + col] = a;
        wp = ALPHA_P * wp + outv * pn * (1.0f + deprn * wp);

        __threadfence();
        grid.sync();
        __threadfence();                          // acquire: invalidate L1 for g_a reads

        // ---- phase 2
        float ia = 0.0f;
        if (use_pre) {
            ia = inp_pre[((size_t)b * TT + t) * NN + col]; // issue early
        } else {
            if (tid < NIN) s_in[tid] = inp_b[t * NIN + tid];
        }

        // build ordered spike list for current slot from the full batch row
        const float* row = g_a + (size_t)slot * BB * NN + (size_t)b * NN;
        unsigned long long msk[4];
        float av[4];
        int cw = 0;
        #pragma unroll
        for (int rr = 0; rr < 4; ++rr) {
            float v = row[wid * 256 + rr * 64 + lane];
            av[rr] = v;
            msk[rr] = __ballot(__float_as_uint(v) != 0u);
            cw += __popcll(msk[rr]);
        }
        if (lane == 0) wcnt[wid] = cw;
        __syncthreads();
        int base = 0;
        for (int w2 = 0; w2 < wid; ++w2) base += wcnt[w2];
        #pragma unroll
        for (int rr = 0; rr < 4; ++rr) {
            unsigned long long m = msk[rr];
            if ((m >> lane) & 1ull) {
                int pos = base + __popcll(m & ((1ull << lane) - 1ull));
                list_e[slot * NN + pos] = (unsigned short)(wid * 256 + rr * 64 + lane);
                list_a[slot * NN + pos] = av[rr];
            }
            base += __popcll(m);
        }
        if (tid == 0) s_count[slot] = wcnt[0] + wcnt[1] + wcnt[2] + wcnt[3];
        __syncthreads();

        // recurrent sum over delayed slots (ascending e within each d)
        float syn = 0.0f;
        const int sl[3] = { (t - d0 + 2 * LL) % LL,
                            (t - d1 + 2 * LL) % LL,
                            (t - d2 + 2 * LL) % LL };
        for (int d = 0; d < DD; ++d) {
            const int s   = sl[d];
            const int cnt = s_count[s];
            const unsigned short* le = &list_e[s * NN];
            const float*          la = &list_a[s * NN];
            if (use_W) {
                const float* Wd = W + (size_t)d * NN * NN + col;
                int i = 0;
                for (; i + 4 <= cnt; i += 4) {
                    int e0 = le[i], e1 = le[i+1], e2 = le[i+2], e3 = le[i+3];
                    float a0 = la[i], a1 = la[i+1], a2 = la[i+2], a3 = la[i+3];
                    float v0 = Wd[(size_t)e0 * NN];
                    float v1 = Wd[(size_t)e1 * NN];
                    float v2 = Wd[(size_t)e2 * NN];
                    float v3 = Wd[(size_t)e3 * NN];
                    syn = fmaf(a0, v0, syn);
                    syn = fmaf(a1, v1, syn);
                    syn = fmaf(a2, v2, syn);
                    syn = fmaf(a3, v3, syn);
                }
                for (; i < cnt; ++i)
                    syn = fmaf(la[i], Wd[(size_t)le[i] * NN], syn);
            } else {
                const float* Dd = dmap + (size_t)d * NN * NN + col;
                for (int i = 0; i < cnt; ++i) {
                    int e = le[i];
                    float wv = Dd[(size_t)e * NN] * (s_sign[e] * fabsf(w_raw[(size_t)e * NN + col]));
                    syn = fmaf(la[i], wv, syn);
                }
            }
        }

        if (!use_pre) {
            #pragma unroll 8
            for (int c = 0; c < NIN; ++c)
                ia = fmaf(s_in[c], w_in[c * NN + col], ia);
        }

        mem = ALPHA_MEM * mem + ia + syn - outv;

        // readout for step t (current slot's list is complete), chunk-0 blocks
        if (chunk == 0 && tid < NOUT) {
            const int cnt = s_count[slot];
            float h = 0.0f;
            for (int i = 0; i < cnt; ++i)
                h += w_out[(int)list_e[slot * NN + i] * NOUT + tid];
            r = ALPHA_MEM_OUT * r + h;
            out_b[t * NOUT + tid] = r;
        }
        // LDS reuse hazards for next step are fenced by grid.sync()
    }
}

// ---------------------------------------------------------------------------
extern "C" void kernel_launch(void* const* d_in, const int* in_sizes, int n_in,
                              void* d_out, int out_size, void* d_ws, size_t ws_size,
                              hipStream_t stream) {
    const float* inputs  = (const float*)d_in[0];
    const float* w       = (const float*)d_in[1];
    const float* w_in    = (const float*)d_in[2];
    const float* w_out   = (const float*)d_in[3];
    const float* w_signs = (const float*)d_in[4];
    const float* dmap    = (const float*)d_in[5];
    const float* p       = (const float*)d_in[6];
    const int*   delays  = (const int*)d_in[7];
    float*       outp    = (float*)d_out;

    const size_t W_el   = (size_t)DD * NN * NN;      // 3.15M
    const size_t ga_el  = (size_t)LL * BB * NN;      // 328K
    const size_t inp_el = (size_t)BB * TT * NN;      // 26.2M

    int use_W = 0, use_pre = 0;
    float *W = nullptr, *g_a = nullptr, *inp_pre = nullptr;
    char* ws = (char*)d_ws;
    if (ws_size >= (W_el + ga_el + inp_el) * 4) {
        use_W = 1; use_pre = 1;
        W       = (float*)ws;
        g_a     = (float*)(ws + W_el * 4);
        inp_pre = (float*)(ws + (W_el + ga_el) * 4);
    } else if (ws_size >= (W_el + ga_el) * 4) {
        use_W = 1;
        W   = (float*)ws;
        g_a = (float*)(ws + W_el * 4);
    } else {
        g_a = (float*)ws;   // 1.25 MB minimum
    }

    if (use_W) {
        const int total = DD * NN * NN;
        build_W<<<(total + 255) / 256, 256, 0, stream>>>(w, w_signs, dmap, W);
    }
    if (use_pre) {
        const int total = BB * TT * NN;
        gemm_in<<<(total + 255) / 256, 256, 0, stream>>>(inputs, w_in, inp_pre);
    }
    {
        const int total = (int)ga_el;
        zero_f<<<(total + 255) / 256, 256, 0, stream>>>(g_a, total);
    }

    void* args[] = {
        (void*)&inputs, (void*)&w_in, (void*)&w_out, (void*)&p, (void*)&delays,
        (void*)&W, (void*)&w, (void*)&w_signs, (void*)&dmap,
        (void*)&g_a, (void*)&inp_pre, (void*)&outp,
        (void*)&use_pre, (void*)&use_W
    };
    hipLaunchCooperativeKernel((const void*)snn_scan,
                               dim3(BB * NCH), dim3(NTH), args, 0, stream);
}

// Round 3
// 51212.292 us; speedup vs baseline: 1.5975x; 1.0666x over previous
//
#include <hip/hip_runtime.h>
#include <cstdint>
#include <cstddef>

// Problem constants
#define BB   64
#define TT   400
#define NN   1024
#define NIN  128
#define NOUT 32
#define DD   3
#define LL   5          // ring length = max(delays)+1, delays = [1,2,4]

#define ALPHA_MEM     0.95f
#define ALPHA_MEM_OUT 0.95f
#define ALPHA_P       0.99f

// ---------------------------------------------------------------------------
// W[d][e][n] = dmap[d][e][n] * (sign[e] * |w[e][n]|)
// ---------------------------------------------------------------------------
__global__ void build_W(const float* __restrict__ w,
                        const float* __restrict__ w_signs,
                        const float* __restrict__ dmap,
                        float* __restrict__ W) {
    int idx = blockIdx.x * blockDim.x + threadIdx.x;
    if (idx >= DD * NN * NN) return;
    int en = idx % (NN * NN);
    int e  = en / NN;
    W[idx] = dmap[idx] * (w_signs[e] * fabsf(w[en]));
}

// inp[b][t][n] = sum_c inputs[b][t][c] * w_in[c][n]
__global__ void gemm_in(const float* __restrict__ inputs,
                        const float* __restrict__ w_in,
                        float* __restrict__ inp) {
    int idx = blockIdx.x * blockDim.x + threadIdx.x;   // BB*TT*NN total
    int n  = idx & (NN - 1);
    int bt = idx >> 10;
    const float* row = inputs + (size_t)bt * NIN;
    float acc = 0.0f;
    #pragma unroll 8
    for (int c = 0; c < NIN; ++c)
        acc = fmaf(row[c], w_in[c * NN + n], acc);
    inp[idx] = acc;
}

// ---------------------------------------------------------------------------
// Scan: one block per batch, 1024 threads (1 neuron/thread), 16 waves/block
// = 4 waves/SIMD. Spike ring kept as LDS lists of (byte-offset, a) pairs.
// ---------------------------------------------------------------------------
__global__ __launch_bounds__(1024) void snn_scan(
    const float* __restrict__ inputs,   // (B,T,NIN)   (fallback path)
    const float* __restrict__ w_in,     // (NIN,N)     (fallback path)
    const float* __restrict__ w_out,    // (N,NOUT)
    const float* __restrict__ p,        // (N)
    const int*   __restrict__ delays,   // (D)
    const float* __restrict__ W,        // (D,N,N) materialized (use_W=1)
    const float* __restrict__ w_raw,    // (N,N)   fallback
    const float* __restrict__ w_signs,  // (N)     fallback
    const float* __restrict__ dmap,     // (D,N,N) fallback
    const float* __restrict__ inp_pre,  // (B,T,N) or null
    float*       __restrict__ out,      // (B,T,NOUT)
    int use_pre, int use_W)
{
    // list entry: (x = bitcast u32 byte-offset e*4096, y = a = 1+wp)
    __shared__ __align__(16) float2 list[LL][NN];   // 40 KB
    __shared__ int   s_count[LL];
    __shared__ int   wcnt[16];
    __shared__ float s_in[NIN];
    __shared__ float s_sign[NN];                    // fallback only

    const int tid  = threadIdx.x;       // neuron index
    const int b    = blockIdx.x;        // batch
    const int lane = tid & 63;
    const int wid  = tid >> 6;

    float mem = 0.0f, wp = 0.0f, r = 0.0f;
    const float pn    = p[tid];
    const float deprn = (pn < 0.0f) ? 1.0f : 0.0f;
    const int d0 = delays[0], d1 = delays[1], d2 = delays[2];

    if (tid < LL) s_count[tid] = 0;
    if (!use_W) {
        for (int k = tid; k < NN; k += 1024) s_sign[k] = w_signs[k];
    }
    __syncthreads();

    const float* inp_b = inputs + (size_t)b * TT * NIN;
    const float* pre_b = use_pre ? (inp_pre + (size_t)b * TT * NN) : nullptr;
    float*       out_b = out + (size_t)b * TT * NOUT;
    const char*  Wb    = (const char*)W;
    const int    col4  = tid * 4;

    for (int t = 0; t < TT; ++t) {
        const int slot = t % LL;

        // ---- phase A: spike decision, ballot, early input load
        const bool  spk = (mem - 1.0f) > 0.0f;
        const float a   = spk ? (1.0f + wp) : 0.0f;
        const unsigned long long mask = __ballot(spk);
        if (lane == 0) wcnt[wid] = __popcll(mask);
        float ia = 0.0f;
        if (use_pre) ia = pre_b[(size_t)t * NN + tid];           // in flight over barrier
        else if (tid < NIN) s_in[tid] = inp_b[t * NIN + tid];
        const float wp_new = ALPHA_P * wp + (spk ? pn * (1.0f + deprn * wp) : 0.0f);
        __syncthreads();

        // ---- phase B: append to current slot's list (ascending e order)
        int base = 0;
        for (int w2 = 0; w2 < wid; ++w2) base += wcnt[w2];
        if (spk) {
            const int pos = base + __popcll(mask & ((1ull << lane) - 1ull));
            float2 ent; ent.x = __uint_as_float((unsigned)(tid << 12)); ent.y = a;
            list[slot][pos] = ent;
        }
        if (tid == 0) {
            int tot = 0;
            #pragma unroll
            for (int w2 = 0; w2 < 16; ++w2) tot += wcnt[w2];
            s_count[slot] = tot;
        }
        wp = wp_new;

        // ---- recurrent gather over delayed slots, 8 accumulators
        float a0 = 0.f, a1 = 0.f, a2 = 0.f, a3 = 0.f,
              a4 = 0.f, a5 = 0.f, a6 = 0.f, a7 = 0.f;
        const int sl[3] = { (t - d0 + 2 * LL) % LL,
                            (t - d1 + 2 * LL) % LL,
                            (t - d2 + 2 * LL) % LL };
        #pragma unroll
        for (int d = 0; d < DD; ++d) {
            const int s   = sl[d];
            const int cnt = s_count[s];     // stable: written ≥1 step ago
            const float2* lp  = list[s];
            const float4* lp4 = (const float4*)lp;
            if (use_W) {
                const char* Wd = Wb + (size_t)d * NN * NN * 4 + col4;
                int i = 0;
                for (; i + 8 <= cnt; i += 8) {
                    const float4 q0 = lp4[(i >> 1) + 0];
                    const float4 q1 = lp4[(i >> 1) + 1];
                    const float4 q2 = lp4[(i >> 1) + 2];
                    const float4 q3 = lp4[(i >> 1) + 3];
                    const float v0 = *(const float*)(Wd + __float_as_uint(q0.x));
                    const float v1 = *(const float*)(Wd + __float_as_uint(q0.z));
                    const float v2 = *(const float*)(Wd + __float_as_uint(q1.x));
                    const float v3 = *(const float*)(Wd + __float_as_uint(q1.z));
                    const float v4 = *(const float*)(Wd + __float_as_uint(q2.x));
                    const float v5 = *(const float*)(Wd + __float_as_uint(q2.z));
                    const float v6 = *(const float*)(Wd + __float_as_uint(q3.x));
                    const float v7 = *(const float*)(Wd + __float_as_uint(q3.z));
                    a0 = fmaf(q0.y, v0, a0);
                    a1 = fmaf(q0.w, v1, a1);
                    a2 = fmaf(q1.y, v2, a2);
                    a3 = fmaf(q1.w, v3, a3);
                    a4 = fmaf(q2.y, v4, a4);
                    a5 = fmaf(q2.w, v5, a5);
                    a6 = fmaf(q3.y, v6, a6);
                    a7 = fmaf(q3.w, v7, a7);
                }
                for (; i < cnt; ++i) {
                    const float2 e = lp[i];
                    a0 = fmaf(e.y, *(const float*)(Wd + __float_as_uint(e.x)), a0);
                }
            } else {
                const char* Dd = (const char*)dmap + (size_t)d * NN * NN * 4 + col4;
                const char* Wr = (const char*)w_raw + col4;
                for (int i = 0; i < cnt; ++i) {
                    const float2 ent = lp[i];
                    const unsigned off = __float_as_uint(ent.x);
                    const int e = off >> 12;
                    const float wv = *(const float*)(Dd + off) *
                                     (s_sign[e] * fabsf(*(const float*)(Wr + off)));
                    a0 = fmaf(ent.y, wv, a0);
                }
            }
        }
        const float syn = ((a0 + a1) + (a2 + a3)) + ((a4 + a5) + (a6 + a7));

        if (!use_pre) {
            #pragma unroll 8
            for (int c = 0; c < NIN; ++c)
                ia = fmaf(s_in[c], w_in[c * NN + tid], ia);
        }

        mem = ALPHA_MEM * mem + ia + syn - (spk ? 1.0f : 0.0f);

        // ---- readout for step t-1 (that slot's list is complete & stable)
        if (tid < NOUT && t > 0) {
            const int ps  = (t - 1) % LL;
            const int cnt = s_count[ps];
            const float2* lp = list[ps];
            float h0 = 0.f, h1 = 0.f;
            int i = 0;
            for (; i + 2 <= cnt; i += 2) {
                const unsigned o0 = __float_as_uint(lp[i].x);
                const unsigned o1 = __float_as_uint(lp[i + 1].x);
                h0 += *(const float*)((const char*)w_out + (o0 >> 5) + tid * 4);
                h1 += *(const float*)((const char*)w_out + (o1 >> 5) + tid * 4);
            }
            if (i < cnt)
                h0 += *(const float*)((const char*)w_out +
                                      (__float_as_uint(lp[i].x) >> 5) + tid * 4);
            r = ALPHA_MEM_OUT * r + (h0 + h1);
            out_b[(t - 1) * NOUT + tid] = r;
        }

        __syncthreads();   // next phase A overwrites slot (t+1)%5 list (read here as d2)
    }

    // final readout for t = TT-1
    if (tid < NOUT) {
        const int ps  = (TT - 1) % LL;
        const int cnt = s_count[ps];
        const float2* lp = list[ps];
        float h = 0.f;
        for (int i = 0; i < cnt; ++i)
            h += *(const float*)((const char*)w_out +
                                 (__float_as_uint(lp[i].x) >> 5) + tid * 4);
        r = ALPHA_MEM_OUT * r + h;
        out_b[(TT - 1) * NOUT + tid] = r;
    }
}

// ---------------------------------------------------------------------------
extern "C" void kernel_launch(void* const* d_in, const int* in_sizes, int n_in,
                              void* d_out, int out_size, void* d_ws, size_t ws_size,
                              hipStream_t stream) {
    const float* inputs  = (const float*)d_in[0];
    const float* w       = (const float*)d_in[1];
    const float* w_in    = (const float*)d_in[2];
    const float* w_out   = (const float*)d_in[3];
    const float* w_signs = (const float*)d_in[4];
    const float* dmap    = (const float*)d_in[5];
    const float* p       = (const float*)d_in[6];
    const int*   delays  = (const int*)d_in[7];
    float*       outp    = (float*)d_out;

    const size_t W_el   = (size_t)DD * NN * NN;   // 3.15M floats (12.6 MB)
    const size_t inp_el = (size_t)BB * TT * NN;   // 26.2M floats (105 MB)

    int use_W = 0, use_pre = 0;
    float *W = nullptr, *inp_pre = nullptr;
    char* ws = (char*)d_ws;
    if (ws_size >= (W_el + inp_el) * 4) {
        use_W = 1; use_pre = 1;
        W       = (float*)ws;
        inp_pre = (float*)(ws + W_el * 4);
    } else if (ws_size >= W_el * 4) {
        use_W = 1;
        W = (float*)ws;
    }

    if (use_W) {
        const int total = DD * NN * NN;
        build_W<<<(total + 255) / 256, 256, 0, stream>>>(w, w_signs, dmap, W);
    }
    if (use_pre) {
        const int total = BB * TT * NN;
        gemm_in<<<(total + 255) / 256, 256, 0, stream>>>(inputs, w_in, inp_pre);
    }

    snn_scan<<<BB, 1024, 0, stream>>>(inputs, w_in, w_out, p, delays,
                                      W, w, w_signs, dmap, inp_pre, outp,
                                      use_pre, use_W);
}